// Round 1
// baseline (242.988 us; speedup 1.0000x reference)
//
#include <hip/hip_runtime.h>

#define N      16384
#define QPW    8            // queries per wave
#define WAVES  8            // waves per block
#define BLOCK  (WAVES * 64) // 512 threads
#define QPB    (QPW * WAVES)   // 64 queries per block
#define NBLK   (N / QPB)       // 256 blocks
#define TILE   2048
#define NTILE  (N / TILE)      // 8 tiles
#define D2MAX  0.25f           // EPS^2: sentinel; contributes exactly 0

__global__ __launch_bounds__(BLOCK) void knn_loss_kernel(
    const float* __restrict__ q, float* __restrict__ block_sum) {
  __shared__ float4 tile[TILE];   // 32 KB
  __shared__ float  wsum[WAVES];

  const int tid  = threadIdx.x;
  const int lane = tid & 63;
  const int wave = tid >> 6;
  const int qbase = blockIdx.x * QPB + wave * QPW;

  // Query coords (broadcast loads, all lanes same address)
  float qx[QPW], qy[QPW], qz[QPW];
#pragma unroll
  for (int k = 0; k < QPW; ++k) {
    qx[k] = q[3 * (qbase + k) + 0];
    qy[k] = q[3 * (qbase + k) + 1];
    qz[k] = q[3 * (qbase + k) + 2];
  }

  // Per-lane sorted top-8 lists (ascending), init to sentinel D2MAX.
  // All indices compile-time -> registers.
  float L[QPW][8];
#pragma unroll
  for (int k = 0; k < QPW; ++k)
#pragma unroll
    for (int s = 0; s < 8; ++s) L[k][s] = D2MAX;

  for (int t = 0; t < NTILE; ++t) {
    const int tb = t * TILE;
    // Stage tile as float4 (xyz + pad) into LDS
#pragma unroll
    for (int s = 0; s < TILE / BLOCK; ++s) {
      const int p  = s * BLOCK + tid;
      const int gp = tb + p;
      tile[p] = make_float4(q[3 * gp + 0], q[3 * gp + 1], q[3 * gp + 2], 0.0f);
    }
    __syncthreads();

#pragma unroll 2
    for (int c = lane; c < TILE; c += 64) {
      const float4 p = tile[c];
      const int j = tb + c;
      float d2[QPW];
      bool hit = false;
#pragma unroll
      for (int k = 0; k < QPW; ++k) {
        const float dx = qx[k] - p.x;
        const float dy = qy[k] - p.y;
        const float dz = qz[k] - p.z;
        d2[k] = dx * dx + dy * dy + dz * dz;
        hit |= (d2[k] < L[k][7]);
      }
      if (hit) {  // rare: exec-masked, skipped when no lane hits
#pragma unroll
        for (int k = 0; k < QPW; ++k) {
          if (d2[k] < L[k][7] && j != (qbase + k)) {
            const float v = d2[k];
            // sorted insert via median shift: new[s] = med3(v, old[s-1], old[s])
            L[k][7] = fmaxf(L[k][6], fminf(v, L[k][7]));
            L[k][6] = fmaxf(L[k][5], fminf(v, L[k][6]));
            L[k][5] = fmaxf(L[k][4], fminf(v, L[k][5]));
            L[k][4] = fmaxf(L[k][3], fminf(v, L[k][4]));
            L[k][3] = fmaxf(L[k][2], fminf(v, L[k][3]));
            L[k][2] = fmaxf(L[k][1], fminf(v, L[k][2]));
            L[k][1] = fmaxf(L[k][0], fminf(v, L[k][1]));
            L[k][0] = fminf(L[k][0], v);
          }
        }
      }
    }
    __syncthreads();
  }

  // Merge the 64 per-lane lists per query: 8 rounds of wave extract-min.
  // Every extracted m <= 0.25, so relu(0.5 - sqrt(m)) == 0.5 - sqrt(m).
  float acc = 0.0f;
#pragma unroll
  for (int k = 0; k < QPW; ++k) {
    float a0 = L[k][0], a1 = L[k][1], a2 = L[k][2], a3 = L[k][3];
    float a4 = L[k][4], a5 = L[k][5], a6 = L[k][6], a7 = L[k][7];
#pragma unroll
    for (int r = 0; r < 8; ++r) {
      float m = a0;
      m = fminf(m, __shfl_xor(m, 1));
      m = fminf(m, __shfl_xor(m, 2));
      m = fminf(m, __shfl_xor(m, 4));
      m = fminf(m, __shfl_xor(m, 8));
      m = fminf(m, __shfl_xor(m, 16));
      m = fminf(m, __shfl_xor(m, 32));
      acc += 0.5f - sqrtf(m);
      // advance exactly one list: lowest lane whose head equals the min
      const unsigned long long bal = __ballot(a0 == m);
      const int first = __ffsll(bal) - 1;
      const bool adv = (lane == first);
      a0 = adv ? a1 : a0;
      a1 = adv ? a2 : a1;
      a2 = adv ? a3 : a2;
      a3 = adv ? a4 : a3;
      a4 = adv ? a5 : a4;
      a5 = adv ? a6 : a5;
      a6 = adv ? a7 : a6;
      a7 = adv ? D2MAX : a7;
    }
  }

  // acc is wave-uniform (same on all lanes): block reduction, deterministic
  if (lane == 0) wsum[wave] = acc;
  __syncthreads();
  if (tid == 0) {
    float s = 0.0f;
#pragma unroll
    for (int w = 0; w < WAVES; ++w) s += wsum[w];
    block_sum[blockIdx.x] = s;
  }
}

__global__ __launch_bounds__(256) void final_reduce_kernel(
    const float* __restrict__ bs, float* __restrict__ out) {
  const int tid = threadIdx.x;
  float v = bs[tid];  // NBLK == 256
#pragma unroll
  for (int off = 1; off < 64; off <<= 1) v += __shfl_xor(v, off);
  __shared__ float r[4];
  if ((tid & 63) == 0) r[tid >> 6] = v;
  __syncthreads();
  if (tid == 0) out[0] = (r[0] + r[1] + r[2] + r[3]) * (1.0f / (float)N);
}

extern "C" void kernel_launch(void* const* d_in, const int* in_sizes, int n_in,
                              void* d_out, int out_size, void* d_ws, size_t ws_size,
                              hipStream_t stream) {
  const float* q = (const float*)d_in[0];
  float* block_sum = (float*)d_ws;  // NBLK floats = 1 KB
  knn_loss_kernel<<<NBLK, BLOCK, 0, stream>>>(q, block_sum);
  final_reduce_kernel<<<1, 256, 0, stream>>>(block_sum, (float*)d_out);
}

// Round 2
// 93.541 us; speedup vs baseline: 2.5977x; 2.5977x over previous
//
#include <hip/hip_runtime.h>

#define N      16384
#define QPW    4               // queries per wave (wave-shared top-8 each)
#define WAVES  8               // waves per block
#define BLOCK  (WAVES * 64)    // 512 threads
#define QPB    (QPW * WAVES)   // 32 queries per block
#define NBLK   (N / QPB)       // 512 blocks -> 16 waves/CU
#define TILE   2048
#define NTILE  (N / TILE)      // 8 tiles
#define D2MAX  0.25f           // EPS^2 sentinel: survives merge contributing exactly 0

__global__ __launch_bounds__(BLOCK) void knn_loss_kernel(
    const float* __restrict__ q, float* __restrict__ block_sum) {
  __shared__ float4 tile[TILE];   // 32 KB: xyz + precomputed |p|^2
  __shared__ float  wsum[WAVES];

  const int tid  = threadIdx.x;
  const int lane = tid & 63;
  const int wave = tid >> 6;
  const int qbase = blockIdx.x * QPB + wave * QPW;

  // Query coords + |q|^2 (broadcast loads; identical fma chain as staging so
  // the self-distance computes to exactly 0)
  float qx[QPW], qy[QPW], qz[QPW], qq[QPW];
#pragma unroll
  for (int k = 0; k < QPW; ++k) {
    const float x = q[3 * (qbase + k) + 0];
    const float y = q[3 * (qbase + k) + 1];
    const float z = q[3 * (qbase + k) + 2];
    qx[k] = x; qy[k] = y; qz[k] = z;
    qq[k] = fmaf(z, z, fmaf(y, y, x * x));
  }

  // Wave-SHARED sorted top-8 per query (ascending d2), replicated uniformly
  // in every lane's registers. All indices compile-time -> registers.
  float L[QPW][8];
#pragma unroll
  for (int k = 0; k < QPW; ++k)
#pragma unroll
    for (int s = 0; s < 8; ++s) L[k][s] = D2MAX;

  for (int t = 0; t < NTILE; ++t) {
    const int tb = t * TILE;
    // Stage tile into LDS (stride-BLOCK writes: conflict-free b128 pattern)
#pragma unroll
    for (int s2 = 0; s2 < TILE / BLOCK; ++s2) {
      const int p  = s2 * BLOCK + tid;
      const int gp = tb + p;
      const float x = q[3 * gp + 0];
      const float y = q[3 * gp + 1];
      const float z = q[3 * gp + 2];
      tile[p] = make_float4(x, y, z, fmaf(z, z, fmaf(y, y, x * x)));
    }
    __syncthreads();

#pragma unroll 2
    for (int s = 0; s < TILE / 64; ++s) {
      const float4 p = tile[s * 64 + lane];
      float d2[QPW];
#pragma unroll
      for (int k = 0; k < QPW; ++k) {
        // d2 = |q|^2 + |p|^2 - 2 q.p   (matches reference arithmetic)
        const float dt = fmaf(qx[k], p.x, fmaf(qy[k], p.y, qz[k] * p.z));
        d2[k] = fmaf(-2.0f, dt, qq[k] + p.w);
      }
      unsigned long long m[QPW];
#pragma unroll
      for (int k = 0; k < QPW; ++k) m[k] = __ballot(d2[k] < L[k][7]);

      if (m[0] | m[1] | m[2] | m[3]) {   // rare once thresholds tighten
        const int jb = tb + s * 64;
#pragma unroll
        for (int k = 0; k < QPW; ++k) {
          unsigned long long mk = m[k];
          if (mk) {
            // Uniform scalar-driven insert loop: every lane does the same
            // insert on its replica, so L stays wave-uniform.
            while (mk) {
              const int i = __ffsll(mk) - 1;
              mk &= mk - 1;
              const float v = __shfl(d2[k], i);   // broadcast (uniform)
              if ((jb + i) != (qbase + k) && v < L[k][7]) {
                L[k][7] = fmaxf(L[k][6], fminf(v, L[k][7]));
                L[k][6] = fmaxf(L[k][5], fminf(v, L[k][6]));
                L[k][5] = fmaxf(L[k][4], fminf(v, L[k][5]));
                L[k][4] = fmaxf(L[k][3], fminf(v, L[k][4]));
                L[k][3] = fmaxf(L[k][2], fminf(v, L[k][3]));
                L[k][2] = fmaxf(L[k][1], fminf(v, L[k][2]));
                L[k][1] = fmaxf(L[k][0], fminf(v, L[k][1]));
                L[k][0] = fminf(L[k][0], v);
              }
            }
          }
        }
      }
    }
    __syncthreads();
  }

  // List is already the exact top-8 (wave-uniform). Every entry <= 0.25 so
  // relu(0.5 - sqrt(d2)) == 0.5 - sqrt(d2); the sentinel contributes 0.
  float acc = 0.0f;
#pragma unroll
  for (int k = 0; k < QPW; ++k)
#pragma unroll
    for (int s = 0; s < 8; ++s)
      acc += 0.5f - sqrtf(fmaxf(L[k][s], 0.0f));

  if (lane == 0) wsum[wave] = acc;
  __syncthreads();
  if (tid == 0) {
    float s = 0.0f;
#pragma unroll
    for (int w = 0; w < WAVES; ++w) s += wsum[w];
    block_sum[blockIdx.x] = s;
  }
}

__global__ __launch_bounds__(256) void final_reduce_kernel(
    const float* __restrict__ bs, float* __restrict__ out) {
  const int tid = threadIdx.x;
  float v = bs[tid] + bs[tid + 256];  // NBLK == 512
#pragma unroll
  for (int off = 1; off < 64; off <<= 1) v += __shfl_xor(v, off);
  __shared__ float r[4];
  if ((tid & 63) == 0) r[tid >> 6] = v;
  __syncthreads();
  if (tid == 0) out[0] = (r[0] + r[1] + r[2] + r[3]) * (1.0f / (float)N);
}

extern "C" void kernel_launch(void* const* d_in, const int* in_sizes, int n_in,
                              void* d_out, int out_size, void* d_ws, size_t ws_size,
                              hipStream_t stream) {
  const float* q = (const float*)d_in[0];
  float* block_sum = (float*)d_ws;  // NBLK floats = 2 KB
  knn_loss_kernel<<<NBLK, BLOCK, 0, stream>>>(q, block_sum);
  final_reduce_kernel<<<1, 256, 0, stream>>>(block_sum, (float*)d_out);
}